// Round 2
// 536.798 us; speedup vs baseline: 1.0524x; 1.0524x over previous
//
#include <hip/hip_runtime.h>

// Patient2Vec forward, MI355X/gfx950.
// Sizes: B=128,S=64,P=32,D=256,E=256,H=128,3H=384,L=2,A=1,O=2.
// Inputs fp32, outputs fp32. alpha == 1.0 exactly (softmax over size-1 axis);
// context = sum_t states.
// R4: GRU rewritten as per-chain MFMA recurrence (Whh in registers, hi/lo
// split); old scalar GRU spilled w[128] to scratch (~3.2 GiB traffic).
// R5/R6: (a) GRU h hi/lo packed into even/odd A-rows, fp16 MFMA with
//     2-pass hi/lo W (fp32-equivalent precision; 24 MFMA/step in 6
//     independent chains of depth 4 — was 36 in 3 chains of depth 12).
//     (b) per-step barrier is lgkmcnt-only (asm waitcnt + builtin s_barrier)
//     so per-step global state stores + xg prefetch loads stay in flight
//     (old __syncthreads drained vmcnt(0) on the critical path 64x).
//     (c) k_final re-parallelized: 128 blocks x 64 lanes, coalesced +
//     shuffle reduce (was 1 block, serial uncoalesced loop).

using u16 = unsigned short;
using u32 = unsigned int;

typedef __bf16    bf16x8 __attribute__((ext_vector_type(8)));
typedef _Float16  f16x8  __attribute__((ext_vector_type(8)));
typedef float     f32x4  __attribute__((ext_vector_type(4)));

__device__ __forceinline__ float bf2f(u16 u) {
  union { u32 i; float f; } v; v.i = ((u32)u) << 16; return v.f;
}
__device__ __forceinline__ u16 f2bf(float f) {
  union { float f; u32 i; } v; v.f = f;
  u32 i = v.i;
  u32 r = (i + 0x7FFFu + ((i >> 16) & 1u)) >> 16;
  return (u16)r;
}
__device__ __forceinline__ float sigm(float x) { return 1.f / (1.f + __expf(-x)); }
__device__ __forceinline__ float tanh_f(float x) { return 1.f - 2.f / (1.f + __expf(2.f * x)); }

// ---------------------------------------------------------------------------
// K0: weight conversion. embed_w fp32 -> hi/lo bf16; Wih fp32 -> bf16.
// ---------------------------------------------------------------------------
__global__ __launch_bounds__(256) void k_cvt(
    const float* __restrict__ embw, const float* __restrict__ Wih,
    u16* __restrict__ embHi, u16* __restrict__ embLo, u16* __restrict__ wihB) {
  const int i = blockIdx.x * 256 + threadIdx.x;
  if (i < 65536) {
    float v = embw[i];
    u16 h = f2bf(v);
    embHi[i] = h;
    embLo[i] = f2bf(v - bf2f(h));
  }
  wihB[i] = f2bf(Wih[i]);
}

// ---------------------------------------------------------------------------
// K1: conv — per (b,s): s_p = dot(inputs[b,s,p,:], conv_w)+cb;
//           conv_all[k] = sum_p s_p * inputs[b,s,p,k]
// fp32 in; emits hi/lo bf16 split of fp32 conv_all.
// ---------------------------------------------------------------------------
__global__ __launch_bounds__(256) void k_conv(
    const float* __restrict__ inp, const float* __restrict__ cw,
    const float* __restrict__ cb, u16* __restrict__ chi, u16* __restrict__ clo) {
  __shared__ float tile[32 * 256];  // 32 KiB
  __shared__ float cwf[256];
  __shared__ float s_p[32];
  const int bs  = blockIdx.x;
  const int tid = threadIdx.x;
  const float* src = inp + (size_t)bs * 8192;
#pragma unroll
  for (int i = 0; i < 8; i++) {
    int idx = i * 1024 + tid * 4;
    *(float4*)&tile[idx] = *(const float4*)&src[idx];
  }
  cwf[tid] = cw[tid];
  __syncthreads();
  const int wv = tid >> 6, ln = tid & 63;
  const float cbf = cb[0];
  for (int pp = 0; pp < 8; pp++) {
    int p = wv * 8 + pp;
    float part = 0.f;
#pragma unroll
    for (int q = 0; q < 4; q++) {
      int k = ln + q * 64;
      part += tile[p * 256 + k] * cwf[k];
    }
    for (int off = 32; off; off >>= 1) part += __shfl_xor(part, off, 64);
    if (ln == 0) s_p[p] = part + cbf;
  }
  __syncthreads();
  float acc = 0.f;
  const int k = tid;
#pragma unroll
  for (int p = 0; p < 32; p++) acc += s_p[p] * tile[p * 256 + k];
  u16 hi = f2bf(acc);
  float lo = acc - bf2f(hi);
  chi[(size_t)bs * 256 + k] = hi;
  clo[(size_t)bs * 256 + k] = f2bf(lo);
}

// ---------------------------------------------------------------------------
// K2: MFMA GEMM  C[m,n] = act( A[m,:]·W[n,:] (+Alo·W) (+A·Wlo) + bias[n] )
// 64x64 tile, 256 thr; verified round 3.
// ---------------------------------------------------------------------------
template <bool HAS_ALO, bool HAS_WLO, bool HAS_BIAS, bool CLIP, bool OUT_BF16>
__global__ __launch_bounds__(256) void k_gemm(
    const u16* __restrict__ A, const u16* __restrict__ Alo,
    const u16* __restrict__ W, const u16* __restrict__ Wlo,
    const float* __restrict__ bias,
    void* __restrict__ Cout, int M, int N, int K) {
  const int LDT = 56;
  __shared__ u16 As[64 * 56];
  __shared__ u16 La[64 * 56];
  __shared__ u16 Ws[64 * 56];
  __shared__ u16 Lw[64 * 56];
  const int tid = threadIdx.x;
  const int m0 = blockIdx.x * 64, n0 = blockIdx.y * 64;
  const int wv = tid >> 6, ln = tid & 63;
  const int lm = ln & 15, lk = (ln >> 4) * 8;
  const int srow = tid >> 2, sgrp = tid & 3;

  f32x4 acc[4];
#pragma unroll
  for (int nt = 0; nt < 4; nt++) acc[nt] = (f32x4){0.f, 0.f, 0.f, 0.f};

  for (int kc = 0; kc < K; kc += 32) {
    __syncthreads();
    *(uint4*)&As[srow * LDT + sgrp * 8] =
        *(const uint4*)&A[(size_t)(m0 + srow) * K + kc + sgrp * 8];
    *(uint4*)&Ws[srow * LDT + sgrp * 8] =
        *(const uint4*)&W[(size_t)(n0 + srow) * K + kc + sgrp * 8];
    if (HAS_ALO)
      *(uint4*)&La[srow * LDT + sgrp * 8] =
          *(const uint4*)&Alo[(size_t)(m0 + srow) * K + kc + sgrp * 8];
    if (HAS_WLO)
      *(uint4*)&Lw[srow * LDT + sgrp * 8] =
          *(const uint4*)&Wlo[(size_t)(n0 + srow) * K + kc + sgrp * 8];
    __syncthreads();

    bf16x8 af = *(const bf16x8*)&As[(wv * 16 + lm) * LDT + lk];
    bf16x8 bfr[4];
#pragma unroll
    for (int nt = 0; nt < 4; nt++)
      bfr[nt] = *(const bf16x8*)&Ws[(nt * 16 + lm) * LDT + lk];
#pragma unroll
    for (int nt = 0; nt < 4; nt++)
      acc[nt] = __builtin_amdgcn_mfma_f32_16x16x32_bf16(af, bfr[nt], acc[nt], 0, 0, 0);
    if (HAS_ALO) {
      bf16x8 lf = *(const bf16x8*)&La[(wv * 16 + lm) * LDT + lk];
#pragma unroll
      for (int nt = 0; nt < 4; nt++)
        acc[nt] = __builtin_amdgcn_mfma_f32_16x16x32_bf16(lf, bfr[nt], acc[nt], 0, 0, 0);
    }
    if (HAS_WLO) {
#pragma unroll
      for (int nt = 0; nt < 4; nt++) {
        bf16x8 wl = *(const bf16x8*)&Lw[(nt * 16 + lm) * LDT + lk];
        acc[nt] = __builtin_amdgcn_mfma_f32_16x16x32_bf16(af, wl, acc[nt], 0, 0, 0);
      }
    }
  }

  const int rbase = m0 + wv * 16 + (ln >> 4) * 4;
#pragma unroll
  for (int nt = 0; nt < 4; nt++) {
    const int col = n0 + nt * 16 + lm;
    const float bv = HAS_BIAS ? bias[col] : 0.f;
#pragma unroll
    for (int r = 0; r < 4; r++) {
      float v = acc[nt][r] + bv;
      if (CLIP) v = fminf(fmaxf(v, -1.f), 1.f);
      const int row = rbase + r;
      if (OUT_BF16)
        ((u16*)Cout)[(size_t)row * N + col] = f2bf(v);
      else
        ((float*)Cout)[(size_t)row * N + col] = v;
    }
  }
}

// ---------------------------------------------------------------------------
// K3: GRU layer via per-chain MFMA recurrence.
// One (b,dir) chain per block; 256 blocks; 512 threads = 8 waves.
// Wave w owns h-dims d in [w*16, w*16+16): gate tiles T=w (r), 8+w (z), 16+w (n).
// R6 scheme: A rows (row = lane&15): EVEN rows carry h_hi fp16, ODD rows
//   carry h_lo = fp16(h - hi). W = Whi + Wlo (fp16 hi/lo split, 24 frags =
//   96 VGPR, loop-invariant in regs). Two MFMA passes (B=Whi, B=Wlo) into
//   SEPARATE accumulators -> 6 independent chains of depth 4.
//   C rows 0/1 land in regs 0/1 of lanes l<16:
//   gh[d] = aH[0]+aH[1]+aL[0]+aL[1]  (~fp32 precision, no cross-lane traffic).
// h exchanged via fp16 hi/lo double-buffered LDS; ONE lgkmcnt-only barrier
// per step (global stores / xg prefetch stay in flight across steps).
// xg register-prefetched one step ahead.
// ---------------------------------------------------------------------------
__global__ __launch_bounds__(512, 2) void k_gru(
    const float* __restrict__ xg,   // [B*S,768], dir cols at dir*384
    const float* __restrict__ WhhL, // [2,384,128] layer slice fp32
    const float* __restrict__ bhhL, // [2,384] layer slice fp32
    u16* __restrict__ st_bf,        // [B,S,256] bf16 or null (layer0)
    float* __restrict__ st_f,       // [B,S,256] fp32 or null (layer1)
    float* __restrict__ ctx) {      // [B,256] fp32 or null (layer1)
  __shared__ __attribute__((aligned(16))) _Float16 hbHi[2][128];
  __shared__ __attribute__((aligned(16))) _Float16 hbLo[2][128];

  const int b   = blockIdx.x >> 1;
  const int dir = blockIdx.x & 1;
  const int tid = threadIdx.x;
  const int w   = tid >> 6, l = tid & 63;
  const int lm  = l & 15;            // col within tile / epilogue dim offset
  const int kw  = (l >> 4) * 8;      // k-window base within 32-chunk
  const int d   = w * 16 + lm;       // this lane's h-dim (epilogue if l<16)

  // --- loop-invariant W-frags (fp16 hi/lo) in registers ---
  f16x8 whi[3][4], wlo[3][4];
#pragma unroll
  for (int tt = 0; tt < 3; tt++) {
#pragma unroll
    for (int kt = 0; kt < 4; kt++) {
      const int row = (tt * 8 + w) * 16 + lm;          // gh row
      const float* p = WhhL + ((size_t)(dir * 384 + row)) * 128 + kt * 32 + kw;
      union { f16x8 v; _Float16 s[8]; } Wh, Wl;
#pragma unroll
      for (int j = 0; j < 8; j++) {
        float v = p[j];
        _Float16 h = (_Float16)v;
        Wh.s[j] = h;
        Wl.s[j] = (_Float16)(v - (float)h);
      }
      whi[tt][kt] = Wh.v;
      wlo[tt][kt] = Wl.v;
    }
  }
  // biases for this lane's dim
  float bhr = 0.f, bhz = 0.f, bhn = 0.f;
  if (l < 16) {
    bhr = bhhL[dir * 384 + d];
    bhz = bhhL[dir * 384 + 128 + d];
    bhn = bhhL[dir * 384 + 256 + d];
  }
  // init h buffer 0
  if (tid < 128) { hbHi[0][tid] = (_Float16)0.f; hbLo[0][tid] = (_Float16)0.f; }

  const float* xbase = xg + (size_t)(b * 64) * 768 + dir * 384 + d;
  float xr = 0.f, xz = 0.f, xn = 0.f;
  if (l < 16) {
    const int t0 = dir ? 63 : 0;
    xr = xbase[t0 * 768];
    xz = xbase[t0 * 768 + 128];
    xn = xbase[t0 * 768 + 256];
  }
  float hold = 0.f, csum = 0.f;
  __syncthreads();

  int cur = 0;
  for (int ti = 0; ti < 64; ti++) {
    const int t = dir ? (63 - ti) : ti;
    // prefetch next step's xg (stays in flight past the barrier)
    float nxr = 0.f, nxz = 0.f, nxn = 0.f;
    if (l < 16 && ti < 63) {
      const int tn = dir ? (62 - ti) : (ti + 1);
      nxr = xbase[tn * 768];
      nxz = xbase[tn * 768 + 128];
      nxn = xbase[tn * 768 + 256];
    }
    // A-frags: parity of this lane's A-row (lane&15) selects hi vs lo.
    // All 4 k-window lanes of a given row share parity (l&1 indep of l>>4).
    const _Float16* hsrc = (l & 1) ? hbLo[cur] : hbHi[cur];
    f16x8 af[4];
#pragma unroll
    for (int kt = 0; kt < 4; kt++)
      af[kt] = *(const f16x8*)&hsrc[kt * 32 + kw];

    f32x4 aH[3], aL[3];
#pragma unroll
    for (int tt = 0; tt < 3; tt++) {
      aH[tt] = (f32x4){0.f, 0.f, 0.f, 0.f};
      aL[tt] = (f32x4){0.f, 0.f, 0.f, 0.f};
    }
#pragma unroll
    for (int kt = 0; kt < 4; kt++) {
#pragma unroll
      for (int tt = 0; tt < 3; tt++) {
        aH[tt] = __builtin_amdgcn_mfma_f32_16x16x32_f16(af[kt], whi[tt][kt], aH[tt], 0, 0, 0);
        aL[tt] = __builtin_amdgcn_mfma_f32_16x16x32_f16(af[kt], wlo[tt][kt], aL[tt], 0, 0, 0);
      }
    }
    const int nxt = cur ^ 1;
    if (l < 16) {
      // rows 0/1 of C = (hi-row)+(lo-row); W hi+lo passes summed.
      const float ghr = aH[0][0] + aH[0][1] + aL[0][0] + aL[0][1];
      const float ghz = aH[1][0] + aH[1][1] + aL[1][0] + aL[1][1];
      const float ghn = aH[2][0] + aH[2][1] + aL[2][0] + aL[2][1];
      const float rg = sigm(xr + bhr + ghr);
      const float zg = sigm(xz + bhz + ghz);
      const float ng = tanh_f(xn + rg * (ghn + bhn));
      const float hn = (1.f - zg) * ng + zg * hold;
      hold = hn;
      csum += hn;
      const _Float16 hh = (_Float16)hn;
      hbHi[nxt][d] = hh;
      hbLo[nxt][d] = (_Float16)(hn - (float)hh);
      const size_t oi = (size_t)(b * 64 + t) * 256 + dir * 128 + d;
      if (st_bf) st_bf[oi] = f2bf(hn);
      if (st_f)  st_f[oi]  = hn;
    }
    // LDS-only barrier: do NOT drain vmcnt (global stores / prefetch loads
    // keep flowing). lgkmcnt(0) makes the h-exchange visible before the
    // barrier; builtin s_barrier keeps compiler ordering semantics.
    asm volatile("s_waitcnt lgkmcnt(0)" ::: "memory");
    __builtin_amdgcn_s_barrier();
    cur = nxt;
    xr = nxr; xz = nxz; xn = nxn;
  }
  if (ctx != nullptr && l < 16)
    ctx[(size_t)b * 256 + dir * 128 + d] = csum;
}

// ---------------------------------------------------------------------------
// K4: final — out = softmax(context @ lin_w^T + lin_b) over O=2; alpha = 1.0.
// R5: 128 blocks x 64 lanes; coalesced ctx reads + wave shuffle reduce.
// ---------------------------------------------------------------------------
__global__ __launch_bounds__(64) void k_final(
    const float* __restrict__ ctx, const float* __restrict__ lw,
    const float* __restrict__ lb, float* __restrict__ out,
    float* __restrict__ alpha) {
  const int b = blockIdx.x;    // 128
  const int l = threadIdx.x;   // 64
  float a0 = 0.f, a1 = 0.f;
#pragma unroll
  for (int q = 0; q < 4; q++) {
    const int k = q * 64 + l;
    const float c = ctx[b * 256 + k];
    a0 += c * lw[k];
    a1 += c * lw[256 + k];
  }
  for (int off = 32; off; off >>= 1) {
    a0 += __shfl_xor(a0, off, 64);
    a1 += __shfl_xor(a1, off, 64);
  }
  alpha[b * 64 + l] = 1.0f;
  if (l == 0) {
    a0 += lb[0];
    a1 += lb[1];
    const float m = fmaxf(a0, a1);
    const float e0 = __expf(a0 - m), e1 = __expf(a1 - m);
    const float s = e0 + e1;
    out[2 * b]     = e0 / s;
    out[2 * b + 1] = e1 / s;
  }
}

// ---------------------------------------------------------------------------
extern "C" void kernel_launch(void* const* d_in, const int* in_sizes, int n_in,
                              void* d_out, int out_size, void* d_ws, size_t ws_size,
                              hipStream_t stream) {
  const float* inp   = (const float*)d_in[0];   // [128,64,32,256]
  const float* convw = (const float*)d_in[1];   // [256]
  const float* convb = (const float*)d_in[2];   // [1]
  const float* embw  = (const float*)d_in[3];   // [256,256]
  const float* Wih   = (const float*)d_in[4];   // [2,2,384,256]
  const float* Whh   = (const float*)d_in[5];   // [2,2,384,128]
  const float* bih   = (const float*)d_in[6];   // [2,2,384]
  const float* bhh   = (const float*)d_in[7];   // [2,2,384]
  // d_in[8] att_w1: unused (softmax over size-1 axis == 1)
  const float* lw    = (const float*)d_in[9];   // [2,256]
  const float* lb    = (const float*)d_in[10];  // [2]

  char* ws = (char*)d_ws;
  u16*   convHi = (u16*)(ws);                         // 4 MiB; reused as states0
  u16*   convLo = (u16*)(ws + 4194304u);              // 4 MiB
  u16*   xbuf   = (u16*)(ws + 8388608u);              // 4 MiB
  u16*   embHi  = (u16*)(ws + 12582912u);             // 128 KiB
  u16*   embLo  = (u16*)(ws + 12713984u);             // 128 KiB
  u16*   wihB   = (u16*)(ws + 12845056u);             // 768 KiB
  float* xgbuf  = (float*)(ws + 13631488u);           // 24 MiB (reused L0/L1)
  u16*   states0 = convHi;

  float* outp    = (float*)d_out;       // [128,2]
  float* statesO = outp + 256;          // [128,64,256]
  float* ctxO    = outp + 2097408;      // [128,256]
  float* alphaO  = outp + 2130176;      // [128,1,64]

  // 0) fp32 weights -> bf16 (embed hi/lo; Wih single)
  k_cvt<<<1536, 256, 0, stream>>>(embw, Wih, embHi, embLo, wihB);

  // 1) conv -> hi/lo split of conv_all
  k_conv<<<8192, 256, 0, stream>>>(inp, convw, convb, convHi, convLo);

  // 2) embed: x = clip((Ahi+Alo)@(Whi+Wlo)^T), bf16 out.  M=8192,N=256,K=256
  dim3 gE(128, 4);
  k_gemm<true, true, false, true, true><<<gE, 256, 0, stream>>>(
      convHi, convLo, embHi, embLo, nullptr, xbuf, 8192, 256, 256);

  // 3) xg layer0 (both dirs fused: Wih[0] flat [768,256]) -> fp32
  dim3 gX(128, 12);
  k_gemm<false, false, true, false, false><<<gX, 256, 0, stream>>>(
      xbuf, nullptr, wihB, nullptr, bih, xgbuf, 8192, 768, 256);

  // 4) GRU layer 0 -> states0 bf16 (ws)
  k_gru<<<256, 512, 0, stream>>>(xgbuf, Whh, bhh, states0, nullptr, nullptr);

  // 5) xg layer1 from states0
  k_gemm<false, false, true, false, false><<<gX, 256, 0, stream>>>(
      states0, nullptr, wihB + 196608, nullptr, bih + 768, xgbuf, 8192, 768, 256);

  // 6) GRU layer 1 -> states fp32 (d_out) + context fp32 (d_out)
  k_gru<<<256, 512, 0, stream>>>(xgbuf, Whh + 98304, bhh + 768,
                                 nullptr, statesO, ctxO);

  // 7) out softmax + alpha ones (fp32)
  k_final<<<128, 64, 0, stream>>>(ctxO, lw, lb, outp, alphaO);
}

// Round 4
// 528.162 us; speedup vs baseline: 1.0696x; 1.0163x over previous
//
#include <hip/hip_runtime.h>

// Patient2Vec forward, MI355X/gfx950.
// Sizes: B=128,S=64,P=32,D=256,E=256,H=128,3H=384,L=2,A=1,O=2.
// Inputs fp32, outputs fp32. alpha == 1.0 exactly (softmax over size-1 axis);
// context = sum_t states.
// R4: GRU as per-chain MFMA recurrence (Whh in registers).
// R6: GRU h hi/lo in even/odd A-rows, fp16 2-pass hi/lo W (24 MFMA/step,
//     6 chains depth 4); lgkmcnt-only per-step barrier; parallel k_final.
// R7/R8: (a) k_gemm K-loop reg-staged 1-deep pipeline: next iter's global
//     loads issued before the MFMA phase, so L2 latency (~200-400cy)
//     overlaps compute instead of sitting between the two barriers.
//     (b) k_cvt folded into k_conv (blocks 0..1535) — one fewer dispatch.
//     (R8 = R7 resubmitted verbatim after infra-side container failure.)

using u16 = unsigned short;
using u32 = unsigned int;

typedef __bf16    bf16x8 __attribute__((ext_vector_type(8)));
typedef _Float16  f16x8  __attribute__((ext_vector_type(8)));
typedef float     f32x4  __attribute__((ext_vector_type(4)));

__device__ __forceinline__ float bf2f(u16 u) {
  union { u32 i; float f; } v; v.i = ((u32)u) << 16; return v.f;
}
__device__ __forceinline__ u16 f2bf(float f) {
  union { float f; u32 i; } v; v.f = f;
  u32 i = v.i;
  u32 r = (i + 0x7FFFu + ((i >> 16) & 1u)) >> 16;
  return (u16)r;
}
__device__ __forceinline__ float sigm(float x) { return 1.f / (1.f + __expf(-x)); }
__device__ __forceinline__ float tanh_f(float x) { return 1.f - 2.f / (1.f + __expf(2.f * x)); }

// ---------------------------------------------------------------------------
// K1: conv — per (b,s): s_p = dot(inputs[b,s,p,:], conv_w)+cb;
//           conv_all[k] = sum_p s_p * inputs[b,s,p,k]
// fp32 in; emits hi/lo bf16 split of fp32 conv_all.
// Blocks 0..1535 also perform the weight conversions (old k_cvt):
//     embed_w fp32 -> hi/lo bf16 (i<65536); Wih fp32 -> bf16 (i<393216).
// ---------------------------------------------------------------------------
__global__ __launch_bounds__(256) void k_conv(
    const float* __restrict__ inp, const float* __restrict__ cw,
    const float* __restrict__ cb, u16* __restrict__ chi, u16* __restrict__ clo,
    const float* __restrict__ embw, const float* __restrict__ Wih,
    u16* __restrict__ embHi, u16* __restrict__ embLo, u16* __restrict__ wihB) {
  __shared__ float tile[32 * 256];  // 32 KiB
  __shared__ float cwf[256];
  __shared__ float s_p[32];
  const int bs  = blockIdx.x;
  const int tid = threadIdx.x;
  const float* src = inp + (size_t)bs * 8192;
#pragma unroll
  for (int i = 0; i < 8; i++) {
    int idx = i * 1024 + tid * 4;
    *(float4*)&tile[idx] = *(const float4*)&src[idx];
  }
  cwf[tid] = cw[tid];
  // folded weight conversion (independent of conv data)
  if (bs < 1536) {
    const int i = bs * 256 + tid;
    if (i < 65536) {
      float v = embw[i];
      u16 h = f2bf(v);
      embHi[i] = h;
      embLo[i] = f2bf(v - bf2f(h));
    }
    wihB[i] = f2bf(Wih[i]);
  }
  __syncthreads();
  const int wv = tid >> 6, ln = tid & 63;
  const float cbf = cb[0];
  for (int pp = 0; pp < 8; pp++) {
    int p = wv * 8 + pp;
    float part = 0.f;
#pragma unroll
    for (int q = 0; q < 4; q++) {
      int k = ln + q * 64;
      part += tile[p * 256 + k] * cwf[k];
    }
    for (int off = 32; off; off >>= 1) part += __shfl_xor(part, off, 64);
    if (ln == 0) s_p[p] = part + cbf;
  }
  __syncthreads();
  float acc = 0.f;
  const int k = tid;
#pragma unroll
  for (int p = 0; p < 32; p++) acc += s_p[p] * tile[p * 256 + k];
  u16 hi = f2bf(acc);
  float lo = acc - bf2f(hi);
  chi[(size_t)bs * 256 + k] = hi;
  clo[(size_t)bs * 256 + k] = f2bf(lo);
}

// ---------------------------------------------------------------------------
// K2: MFMA GEMM  C[m,n] = act( A[m,:]·W[n,:] (+Alo·W) (+A·Wlo) + bias[n] )
// 64x64 tile, 256 thr; verified round 3.
// Reg-staged 1-deep pipeline — next K-iter's global loads are issued
// right after the ds_writes, overlapping L2 latency with frag reads + MFMA.
// Barrier structure, LDS layout, indices identical to verified version.
// ---------------------------------------------------------------------------
template <bool HAS_ALO, bool HAS_WLO, bool HAS_BIAS, bool CLIP, bool OUT_BF16>
__global__ __launch_bounds__(256) void k_gemm(
    const u16* __restrict__ A, const u16* __restrict__ Alo,
    const u16* __restrict__ W, const u16* __restrict__ Wlo,
    const float* __restrict__ bias,
    void* __restrict__ Cout, int M, int N, int K) {
  const int LDT = 56;
  __shared__ u16 As[64 * 56];
  __shared__ u16 La[64 * 56];
  __shared__ u16 Ws[64 * 56];
  __shared__ u16 Lw[64 * 56];
  const int tid = threadIdx.x;
  const int m0 = blockIdx.x * 64, n0 = blockIdx.y * 64;
  const int wv = tid >> 6, ln = tid & 63;
  const int lm = ln & 15, lk = (ln >> 4) * 8;
  const int srow = tid >> 2, sgrp = tid & 3;

  const size_t aRow = (size_t)(m0 + srow) * K + sgrp * 8;
  const size_t wRow = (size_t)(n0 + srow) * K + sgrp * 8;

  f32x4 acc[4];
#pragma unroll
  for (int nt = 0; nt < 4; nt++) acc[nt] = (f32x4){0.f, 0.f, 0.f, 0.f};

  // prologue: stage K-chunk 0 into registers
  uint4 rA = *(const uint4*)&A[aRow];
  uint4 rW = *(const uint4*)&W[wRow];
  uint4 rLa, rLw;
  if (HAS_ALO) rLa = *(const uint4*)&Alo[aRow];
  if (HAS_WLO) rLw = *(const uint4*)&Wlo[wRow];

  const int nIter = K >> 5;
  for (int it = 0; it < nIter; it++) {
    __syncthreads();   // previous iteration's frag reads complete
    *(uint4*)&As[srow * LDT + sgrp * 8] = rA;
    *(uint4*)&Ws[srow * LDT + sgrp * 8] = rW;
    if (HAS_ALO) *(uint4*)&La[srow * LDT + sgrp * 8] = rLa;
    if (HAS_WLO) *(uint4*)&Lw[srow * LDT + sgrp * 8] = rLw;
    // issue next chunk's loads (in flight across barrier + MFMA phase)
    if (it + 1 < nIter) {
      const int kc = (it + 1) * 32;
      rA = *(const uint4*)&A[aRow + kc];
      rW = *(const uint4*)&W[wRow + kc];
      if (HAS_ALO) rLa = *(const uint4*)&Alo[aRow + kc];
      if (HAS_WLO) rLw = *(const uint4*)&Wlo[wRow + kc];
    }
    __syncthreads();   // ds_writes visible

    bf16x8 af = *(const bf16x8*)&As[(wv * 16 + lm) * LDT + lk];
    bf16x8 bfr[4];
#pragma unroll
    for (int nt = 0; nt < 4; nt++)
      bfr[nt] = *(const bf16x8*)&Ws[(nt * 16 + lm) * LDT + lk];
#pragma unroll
    for (int nt = 0; nt < 4; nt++)
      acc[nt] = __builtin_amdgcn_mfma_f32_16x16x32_bf16(af, bfr[nt], acc[nt], 0, 0, 0);
    if (HAS_ALO) {
      bf16x8 lf = *(const bf16x8*)&La[(wv * 16 + lm) * LDT + lk];
#pragma unroll
      for (int nt = 0; nt < 4; nt++)
        acc[nt] = __builtin_amdgcn_mfma_f32_16x16x32_bf16(lf, bfr[nt], acc[nt], 0, 0, 0);
    }
    if (HAS_WLO) {
#pragma unroll
      for (int nt = 0; nt < 4; nt++) {
        bf16x8 wl = *(const bf16x8*)&Lw[(nt * 16 + lm) * LDT + lk];
        acc[nt] = __builtin_amdgcn_mfma_f32_16x16x32_bf16(af, wl, acc[nt], 0, 0, 0);
      }
    }
  }

  const int rbase = m0 + wv * 16 + (ln >> 4) * 4;
#pragma unroll
  for (int nt = 0; nt < 4; nt++) {
    const int col = n0 + nt * 16 + lm;
    const float bv = HAS_BIAS ? bias[col] : 0.f;
#pragma unroll
    for (int r = 0; r < 4; r++) {
      float v = acc[nt][r] + bv;
      if (CLIP) v = fminf(fmaxf(v, -1.f), 1.f);
      const int row = rbase + r;
      if (OUT_BF16)
        ((u16*)Cout)[(size_t)row * N + col] = f2bf(v);
      else
        ((float*)Cout)[(size_t)row * N + col] = v;
    }
  }
}

// ---------------------------------------------------------------------------
// K3: GRU layer via per-chain MFMA recurrence.
// One (b,dir) chain per block; 256 blocks; 512 threads = 8 waves.
// Wave w owns h-dims d in [w*16, w*16+16): gate tiles T=w (r), 8+w (z), 16+w (n).
// A rows (row = lane&15): EVEN rows carry h_hi fp16, ODD rows carry
//   h_lo = fp16(h - hi). W = Whi + Wlo (fp16 hi/lo split, 24 frags = 96 VGPR,
//   loop-invariant in regs). Two MFMA passes (B=Whi, B=Wlo) into SEPARATE
//   accumulators -> 6 independent chains of depth 4.
//   gh[d] = aH[0]+aH[1]+aL[0]+aL[1]  (~fp32 precision, no cross-lane traffic).
// h exchanged via fp16 hi/lo double-buffered LDS; ONE lgkmcnt-only barrier
// per step (global stores / xg prefetch stay in flight across steps).
// xg register-prefetched one step ahead.
// ---------------------------------------------------------------------------
__global__ __launch_bounds__(512, 2) void k_gru(
    const float* __restrict__ xg,   // [B*S,768], dir cols at dir*384
    const float* __restrict__ WhhL, // [2,384,128] layer slice fp32
    const float* __restrict__ bhhL, // [2,384] layer slice fp32
    u16* __restrict__ st_bf,        // [B,S,256] bf16 or null (layer0)
    float* __restrict__ st_f,       // [B,S,256] fp32 or null (layer1)
    float* __restrict__ ctx) {      // [B,256] fp32 or null (layer1)
  __shared__ __attribute__((aligned(16))) _Float16 hbHi[2][128];
  __shared__ __attribute__((aligned(16))) _Float16 hbLo[2][128];

  const int b   = blockIdx.x >> 1;
  const int dir = blockIdx.x & 1;
  const int tid = threadIdx.x;
  const int w   = tid >> 6, l = tid & 63;
  const int lm  = l & 15;            // col within tile / epilogue dim offset
  const int kw  = (l >> 4) * 8;      // k-window base within 32-chunk
  const int d   = w * 16 + lm;       // this lane's h-dim (epilogue if l<16)

  // --- loop-invariant W-frags (fp16 hi/lo) in registers ---
  f16x8 whi[3][4], wlo[3][4];
#pragma unroll
  for (int tt = 0; tt < 3; tt++) {
#pragma unroll
    for (int kt = 0; kt < 4; kt++) {
      const int row = (tt * 8 + w) * 16 + lm;          // gh row
      const float* p = WhhL + ((size_t)(dir * 384 + row)) * 128 + kt * 32 + kw;
      union { f16x8 v; _Float16 s[8]; } Wh, Wl;
#pragma unroll
      for (int j = 0; j < 8; j++) {
        float v = p[j];
        _Float16 h = (_Float16)v;
        Wh.s[j] = h;
        Wl.s[j] = (_Float16)(v - (float)h);
      }
      whi[tt][kt] = Wh.v;
      wlo[tt][kt] = Wl.v;
    }
  }
  // biases for this lane's dim
  float bhr = 0.f, bhz = 0.f, bhn = 0.f;
  if (l < 16) {
    bhr = bhhL[dir * 384 + d];
    bhz = bhhL[dir * 384 + 128 + d];
    bhn = bhhL[dir * 384 + 256 + d];
  }
  // init h buffer 0
  if (tid < 128) { hbHi[0][tid] = (_Float16)0.f; hbLo[0][tid] = (_Float16)0.f; }

  const float* xbase = xg + (size_t)(b * 64) * 768 + dir * 384 + d;
  float xr = 0.f, xz = 0.f, xn = 0.f;
  if (l < 16) {
    const int t0 = dir ? 63 : 0;
    xr = xbase[t0 * 768];
    xz = xbase[t0 * 768 + 128];
    xn = xbase[t0 * 768 + 256];
  }
  float hold = 0.f, csum = 0.f;
  __syncthreads();

  int cur = 0;
  for (int ti = 0; ti < 64; ti++) {
    const int t = dir ? (63 - ti) : ti;
    // prefetch next step's xg (stays in flight past the barrier)
    float nxr = 0.f, nxz = 0.f, nxn = 0.f;
    if (l < 16 && ti < 63) {
      const int tn = dir ? (62 - ti) : (ti + 1);
      nxr = xbase[tn * 768];
      nxz = xbase[tn * 768 + 128];
      nxn = xbase[tn * 768 + 256];
    }
    // A-frags: parity of this lane's A-row (lane&15) selects hi vs lo.
    const _Float16* hsrc = (l & 1) ? hbLo[cur] : hbHi[cur];
    f16x8 af[4];
#pragma unroll
    for (int kt = 0; kt < 4; kt++)
      af[kt] = *(const f16x8*)&hsrc[kt * 32 + kw];

    f32x4 aH[3], aL[3];
#pragma unroll
    for (int tt = 0; tt < 3; tt++) {
      aH[tt] = (f32x4){0.f, 0.f, 0.f, 0.f};
      aL[tt] = (f32x4){0.f, 0.f, 0.f, 0.f};
    }
#pragma unroll
    for (int kt = 0; kt < 4; kt++) {
#pragma unroll
      for (int tt = 0; tt < 3; tt++) {
        aH[tt] = __builtin_amdgcn_mfma_f32_16x16x32_f16(af[kt], whi[tt][kt], aH[tt], 0, 0, 0);
        aL[tt] = __builtin_amdgcn_mfma_f32_16x16x32_f16(af[kt], wlo[tt][kt], aL[tt], 0, 0, 0);
      }
    }
    const int nxt = cur ^ 1;
    if (l < 16) {
      // rows 0/1 of C = (hi-row)+(lo-row); W hi+lo passes summed.
      const float ghr = aH[0][0] + aH[0][1] + aL[0][0] + aL[0][1];
      const float ghz = aH[1][0] + aH[1][1] + aL[1][0] + aL[1][1];
      const float ghn = aH[2][0] + aH[2][1] + aL[2][0] + aL[2][1];
      const float rg = sigm(xr + bhr + ghr);
      const float zg = sigm(xz + bhz + ghz);
      const float ng = tanh_f(xn + rg * (ghn + bhn));
      const float hn = (1.f - zg) * ng + zg * hold;
      hold = hn;
      csum += hn;
      const _Float16 hh = (_Float16)hn;
      hbHi[nxt][d] = hh;
      hbLo[nxt][d] = (_Float16)(hn - (float)hh);
      const size_t oi = (size_t)(b * 64 + t) * 256 + dir * 128 + d;
      if (st_bf) st_bf[oi] = f2bf(hn);
      if (st_f)  st_f[oi]  = hn;
    }
    // LDS-only barrier: do NOT drain vmcnt (global stores / prefetch loads
    // keep flowing). lgkmcnt(0) makes the h-exchange visible before the
    // barrier; builtin s_barrier keeps compiler ordering semantics.
    asm volatile("s_waitcnt lgkmcnt(0)" ::: "memory");
    __builtin_amdgcn_s_barrier();
    cur = nxt;
    xr = nxr; xz = nxz; xn = nxn;
  }
  if (ctx != nullptr && l < 16)
    ctx[(size_t)b * 256 + dir * 128 + d] = csum;
}

// ---------------------------------------------------------------------------
// K4: final — out = softmax(context @ lin_w^T + lin_b) over O=2; alpha = 1.0.
// 128 blocks x 64 lanes; coalesced ctx reads + wave shuffle reduce.
// ---------------------------------------------------------------------------
__global__ __launch_bounds__(64) void k_final(
    const float* __restrict__ ctx, const float* __restrict__ lw,
    const float* __restrict__ lb, float* __restrict__ out,
    float* __restrict__ alpha) {
  const int b = blockIdx.x;    // 128
  const int l = threadIdx.x;   // 64
  float a0 = 0.f, a1 = 0.f;
#pragma unroll
  for (int q = 0; q < 4; q++) {
    const int k = q * 64 + l;
    const float c = ctx[b * 256 + k];
    a0 += c * lw[k];
    a1 += c * lw[256 + k];
  }
  for (int off = 32; off; off >>= 1) {
    a0 += __shfl_xor(a0, off, 64);
    a1 += __shfl_xor(a1, off, 64);
  }
  alpha[b * 64 + l] = 1.0f;
  if (l == 0) {
    a0 += lb[0];
    a1 += lb[1];
    const float m = fmaxf(a0, a1);
    const float e0 = __expf(a0 - m), e1 = __expf(a1 - m);
    const float s = e0 + e1;
    out[2 * b]     = e0 / s;
    out[2 * b + 1] = e1 / s;
  }
}

// ---------------------------------------------------------------------------
extern "C" void kernel_launch(void* const* d_in, const int* in_sizes, int n_in,
                              void* d_out, int out_size, void* d_ws, size_t ws_size,
                              hipStream_t stream) {
  const float* inp   = (const float*)d_in[0];   // [128,64,32,256]
  const float* convw = (const float*)d_in[1];   // [256]
  const float* convb = (const float*)d_in[2];   // [1]
  const float* embw  = (const float*)d_in[3];   // [256,256]
  const float* Wih   = (const float*)d_in[4];   // [2,2,384,256]
  const float* Whh   = (const float*)d_in[5];   // [2,2,384,128]
  const float* bih   = (const float*)d_in[6];   // [2,2,384]
  const float* bhh   = (const float*)d_in[7];   // [2,2,384]
  // d_in[8] att_w1: unused (softmax over size-1 axis == 1)
  const float* lw    = (const float*)d_in[9];   // [2,256]
  const float* lb    = (const float*)d_in[10];  // [2]

  char* ws = (char*)d_ws;
  u16*   convHi = (u16*)(ws);                         // 4 MiB; reused as states0
  u16*   convLo = (u16*)(ws + 4194304u);              // 4 MiB
  u16*   xbuf   = (u16*)(ws + 8388608u);              // 4 MiB
  u16*   embHi  = (u16*)(ws + 12582912u);             // 128 KiB
  u16*   embLo  = (u16*)(ws + 12713984u);             // 128 KiB
  u16*   wihB   = (u16*)(ws + 12845056u);             // 768 KiB
  float* xgbuf  = (float*)(ws + 13631488u);           // 24 MiB (reused L0/L1)
  u16*   states0 = convHi;

  float* outp    = (float*)d_out;       // [128,2]
  float* statesO = outp + 256;          // [128,64,256]
  float* ctxO    = outp + 2097408;      // [128,256]
  float* alphaO  = outp + 2130176;      // [128,1,64]

  // 1) conv -> hi/lo split of conv_all; blocks 0..1535 also convert weights
  k_conv<<<8192, 256, 0, stream>>>(inp, convw, convb, convHi, convLo,
                                   embw, Wih, embHi, embLo, wihB);

  // 2) embed: x = clip((Ahi+Alo)@(Whi+Wlo)^T), bf16 out.  M=8192,N=256,K=256
  dim3 gE(128, 4);
  k_gemm<true, true, false, true, true><<<gE, 256, 0, stream>>>(
      convHi, convLo, embHi, embLo, nullptr, xbuf, 8192, 256, 256);

  // 3) xg layer0 (both dirs fused: Wih[0] flat [768,256]) -> fp32
  dim3 gX(128, 12);
  k_gemm<false, false, true, false, false><<<gX, 256, 0, stream>>>(
      xbuf, nullptr, wihB, nullptr, bih, xgbuf, 8192, 768, 256);

  // 4) GRU layer 0 -> states0 bf16 (ws)
  k_gru<<<256, 512, 0, stream>>>(xgbuf, Whh, bhh, states0, nullptr, nullptr);

  // 5) xg layer1 from states0
  k_gemm<false, false, true, false, false><<<gX, 256, 0, stream>>>(
      states0, nullptr, wihB + 196608, nullptr, bih + 768, xgbuf, 8192, 768, 256);

  // 6) GRU layer 1 -> states fp32 (d_out) + context fp32 (d_out)
  k_gru<<<256, 512, 0, stream>>>(xgbuf, Whh + 98304, bhh + 768,
                                 nullptr, statesO, ctxO);

  // 7) out softmax + alpha ones (fp32)
  k_final<<<128, 64, 0, stream>>>(ctxO, lw, lb, outp, alphaO);
}

// Round 5
// 527.189 us; speedup vs baseline: 1.0716x; 1.0018x over previous
//
#include <hip/hip_runtime.h>

// Patient2Vec forward, MI355X/gfx950.
// Sizes: B=128,S=64,P=32,D=256,E=256,H=128,3H=384,L=2,A=1,O=2.
// Inputs fp32, outputs fp32. alpha == 1.0 exactly (softmax over size-1 axis);
// context = sum_t states.
// R4: GRU as per-chain MFMA recurrence (Whh in registers).
// R6: GRU h hi/lo in even/odd A-rows, fp16 2-pass hi/lo W (24 MFMA/step,
//     6 chains depth 4); lgkmcnt-only per-step barrier; parallel k_final.
// R7/R8: k_gemm reg-staged 1-deep pipeline; k_cvt folded into k_conv.
// R9: xg GEMM fused into k_gru as a per-block prologue. Each (b,dir) block
//     stages x_b (64x256 bf16) in padded LDS, computes xg = x_b@WihD^T+bihD
//     (96 MFMA/wave, gate-tile mapping tt*8+w matching the recurrence),
//     writes its private 98KB xg chunk (same-XCD L2-resident), then runs
//     the recurrence. Removes 2 GEMM dispatches and the full-grid xg
//     barrier from the critical path. xg accumulation order identical to
//     the old k_gemm -> bit-identical numerics.

using u16 = unsigned short;
using u32 = unsigned int;

typedef __bf16    bf16x8 __attribute__((ext_vector_type(8)));
typedef _Float16  f16x8  __attribute__((ext_vector_type(8)));
typedef float     f32x4  __attribute__((ext_vector_type(4)));

__device__ __forceinline__ float bf2f(u16 u) {
  union { u32 i; float f; } v; v.i = ((u32)u) << 16; return v.f;
}
__device__ __forceinline__ u16 f2bf(float f) {
  union { float f; u32 i; } v; v.f = f;
  u32 i = v.i;
  u32 r = (i + 0x7FFFu + ((i >> 16) & 1u)) >> 16;
  return (u16)r;
}
__device__ __forceinline__ float sigm(float x) { return 1.f / (1.f + __expf(-x)); }
__device__ __forceinline__ float tanh_f(float x) { return 1.f - 2.f / (1.f + __expf(2.f * x)); }

// ---------------------------------------------------------------------------
// K1: conv — per (b,s): s_p = dot(inputs[b,s,p,:], conv_w)+cb;
//           conv_all[k] = sum_p s_p * inputs[b,s,p,k]
// fp32 in; emits hi/lo bf16 split of fp32 conv_all.
// Blocks 0..1535 also perform the weight conversions:
//     embed_w fp32 -> hi/lo bf16 (i<65536); Wih fp32 -> bf16 (i<393216).
// ---------------------------------------------------------------------------
__global__ __launch_bounds__(256) void k_conv(
    const float* __restrict__ inp, const float* __restrict__ cw,
    const float* __restrict__ cb, u16* __restrict__ chi, u16* __restrict__ clo,
    const float* __restrict__ embw, const float* __restrict__ Wih,
    u16* __restrict__ embHi, u16* __restrict__ embLo, u16* __restrict__ wihB) {
  __shared__ float tile[32 * 256];  // 32 KiB
  __shared__ float cwf[256];
  __shared__ float s_p[32];
  const int bs  = blockIdx.x;
  const int tid = threadIdx.x;
  const float* src = inp + (size_t)bs * 8192;
#pragma unroll
  for (int i = 0; i < 8; i++) {
    int idx = i * 1024 + tid * 4;
    *(float4*)&tile[idx] = *(const float4*)&src[idx];
  }
  cwf[tid] = cw[tid];
  // folded weight conversion (independent of conv data)
  if (bs < 1536) {
    const int i = bs * 256 + tid;
    if (i < 65536) {
      float v = embw[i];
      u16 h = f2bf(v);
      embHi[i] = h;
      embLo[i] = f2bf(v - bf2f(h));
    }
    wihB[i] = f2bf(Wih[i]);
  }
  __syncthreads();
  const int wv = tid >> 6, ln = tid & 63;
  const float cbf = cb[0];
  for (int pp = 0; pp < 8; pp++) {
    int p = wv * 8 + pp;
    float part = 0.f;
#pragma unroll
    for (int q = 0; q < 4; q++) {
      int k = ln + q * 64;
      part += tile[p * 256 + k] * cwf[k];
    }
    for (int off = 32; off; off >>= 1) part += __shfl_xor(part, off, 64);
    if (ln == 0) s_p[p] = part + cbf;
  }
  __syncthreads();
  float acc = 0.f;
  const int k = tid;
#pragma unroll
  for (int p = 0; p < 32; p++) acc += s_p[p] * tile[p * 256 + k];
  u16 hi = f2bf(acc);
  float lo = acc - bf2f(hi);
  chi[(size_t)bs * 256 + k] = hi;
  clo[(size_t)bs * 256 + k] = f2bf(lo);
}

// ---------------------------------------------------------------------------
// K2: MFMA GEMM  C[m,n] = act( A[m,:]·W[n,:] (+Alo·W) (+A·Wlo) + bias[n] )
// 64x64 tile, 256 thr; reg-staged 1-deep pipeline (R7). Used for embed only.
// ---------------------------------------------------------------------------
template <bool HAS_ALO, bool HAS_WLO, bool HAS_BIAS, bool CLIP, bool OUT_BF16>
__global__ __launch_bounds__(256) void k_gemm(
    const u16* __restrict__ A, const u16* __restrict__ Alo,
    const u16* __restrict__ W, const u16* __restrict__ Wlo,
    const float* __restrict__ bias,
    void* __restrict__ Cout, int M, int N, int K) {
  const int LDT = 56;
  __shared__ u16 As[64 * 56];
  __shared__ u16 La[64 * 56];
  __shared__ u16 Ws[64 * 56];
  __shared__ u16 Lw[64 * 56];
  const int tid = threadIdx.x;
  const int m0 = blockIdx.x * 64, n0 = blockIdx.y * 64;
  const int wv = tid >> 6, ln = tid & 63;
  const int lm = ln & 15, lk = (ln >> 4) * 8;
  const int srow = tid >> 2, sgrp = tid & 3;

  const size_t aRow = (size_t)(m0 + srow) * K + sgrp * 8;
  const size_t wRow = (size_t)(n0 + srow) * K + sgrp * 8;

  f32x4 acc[4];
#pragma unroll
  for (int nt = 0; nt < 4; nt++) acc[nt] = (f32x4){0.f, 0.f, 0.f, 0.f};

  // prologue: stage K-chunk 0 into registers
  uint4 rA = *(const uint4*)&A[aRow];
  uint4 rW = *(const uint4*)&W[wRow];
  uint4 rLa, rLw;
  if (HAS_ALO) rLa = *(const uint4*)&Alo[aRow];
  if (HAS_WLO) rLw = *(const uint4*)&Wlo[wRow];

  const int nIter = K >> 5;
  for (int it = 0; it < nIter; it++) {
    __syncthreads();   // previous iteration's frag reads complete
    *(uint4*)&As[srow * LDT + sgrp * 8] = rA;
    *(uint4*)&Ws[srow * LDT + sgrp * 8] = rW;
    if (HAS_ALO) *(uint4*)&La[srow * LDT + sgrp * 8] = rLa;
    if (HAS_WLO) *(uint4*)&Lw[srow * LDT + sgrp * 8] = rLw;
    // issue next chunk's loads (in flight across barrier + MFMA phase)
    if (it + 1 < nIter) {
      const int kc = (it + 1) * 32;
      rA = *(const uint4*)&A[aRow + kc];
      rW = *(const uint4*)&W[wRow + kc];
      if (HAS_ALO) rLa = *(const uint4*)&Alo[aRow + kc];
      if (HAS_WLO) rLw = *(const uint4*)&Wlo[wRow + kc];
    }
    __syncthreads();   // ds_writes visible

    bf16x8 af = *(const bf16x8*)&As[(wv * 16 + lm) * LDT + lk];
    bf16x8 bfr[4];
#pragma unroll
    for (int nt = 0; nt < 4; nt++)
      bfr[nt] = *(const bf16x8*)&Ws[(nt * 16 + lm) * LDT + lk];
#pragma unroll
    for (int nt = 0; nt < 4; nt++)
      acc[nt] = __builtin_amdgcn_mfma_f32_16x16x32_bf16(af, bfr[nt], acc[nt], 0, 0, 0);
    if (HAS_ALO) {
      bf16x8 lf = *(const bf16x8*)&La[(wv * 16 + lm) * LDT + lk];
#pragma unroll
      for (int nt = 0; nt < 4; nt++)
        acc[nt] = __builtin_amdgcn_mfma_f32_16x16x32_bf16(lf, bfr[nt], acc[nt], 0, 0, 0);
    }
    if (HAS_WLO) {
#pragma unroll
      for (int nt = 0; nt < 4; nt++) {
        bf16x8 wl = *(const bf16x8*)&Lw[(nt * 16 + lm) * LDT + lk];
        acc[nt] = __builtin_amdgcn_mfma_f32_16x16x32_bf16(af, wl, acc[nt], 0, 0, 0);
      }
    }
  }

  const int rbase = m0 + wv * 16 + (ln >> 4) * 4;
#pragma unroll
  for (int nt = 0; nt < 4; nt++) {
    const int col = n0 + nt * 16 + lm;
    const float bv = HAS_BIAS ? bias[col] : 0.f;
#pragma unroll
    for (int r = 0; r < 4; r++) {
      float v = acc[nt][r] + bv;
      if (CLIP) v = fminf(fmaxf(v, -1.f), 1.f);
      const int row = rbase + r;
      if (OUT_BF16)
        ((u16*)Cout)[(size_t)row * N + col] = f2bf(v);
      else
        ((float*)Cout)[(size_t)row * N + col] = v;
    }
  }
}

// ---------------------------------------------------------------------------
// K3: GRU layer, fused xg GEMM prologue + per-chain MFMA recurrence.
// One (b,dir) chain per block; 256 blocks; 512 threads = 8 waves.
//
// Prologue: xg[64,384] = x_b[64,256](bf16) @ WihD^T + bihD, written to the
//   block's private fp32 chunk of the xg workspace (same-XCD L2-resident).
//   x_b staged in LDS with +8 u16 row pad (row stride 528B -> 2-way bank
//   aliasing only, free per m136). Wave w computes gate tiles tt*8+w
//   (same mapping as recurrence), all 4 m-tiles, K=256 in 8 chunks —
//   accumulation order identical to the old k_gemm xg dispatch.
//
// Recurrence: wave w owns h-dims d in [w*16, w*16+16); gate tiles
//   T = w (r), 8+w (z), 16+w (n). A rows (row = lane&15): EVEN rows carry
//   h_hi fp16, ODD rows h_lo = fp16(h-hi). W = Whi+Wlo fp16 split in regs
//   (24 frags = 96 VGPR). 2 MFMA passes into separate accumulators ->
//   6 independent chains of depth 4. gh[d] = aH[0]+aH[1]+aL[0]+aL[1].
//   h exchanged via fp16 hi/lo double-buffered LDS; ONE lgkmcnt-only
//   barrier per step (global stores / xg prefetch stay in flight).
//   xg register-prefetched one step ahead.
// ---------------------------------------------------------------------------
__global__ __launch_bounds__(512, 2) void k_gru(
    const u16* __restrict__ xsrc,   // [8192,256] bf16 (xbuf or states0)
    const u16* __restrict__ wihL,   // [2*384,256] bf16 layer slice
    const float* __restrict__ bihL, // [2*384] layer slice
    const float* __restrict__ WhhL, // [2,384,128] layer slice fp32
    const float* __restrict__ bhhL, // [2,384] layer slice fp32
    float* __restrict__ xg,         // [128*2, 64*384] fp32 scratch (ws)
    u16* __restrict__ st_bf,        // [B,S,256] bf16 or null (layer0)
    float* __restrict__ st_f,       // [B,S,256] fp32 or null (layer1)
    float* __restrict__ ctx) {      // [B,256] fp32 or null (layer1)
  __shared__ __attribute__((aligned(16))) u16 xt[64 * 264];   // 33,792 B
  __shared__ __attribute__((aligned(16))) _Float16 hbHi[2][128];
  __shared__ __attribute__((aligned(16))) _Float16 hbLo[2][128];

  const int b   = blockIdx.x >> 1;
  const int dir = blockIdx.x & 1;
  const int tid = threadIdx.x;
  const int w   = tid >> 6, l = tid & 63;
  const int lm  = l & 15;            // A/B-row within tile / epilogue dim
  const int kw  = (l >> 4) * 8;      // k-window base within 32-chunk
  const int d   = w * 16 + lm;       // this lane's h-dim (epilogue if l<16)

  // --- loop-invariant Whh-frags (fp16 hi/lo) in registers ---
  f16x8 whi[3][4], wlo[3][4];
#pragma unroll
  for (int tt = 0; tt < 3; tt++) {
#pragma unroll
    for (int kt = 0; kt < 4; kt++) {
      const int row = (tt * 8 + w) * 16 + lm;          // gh row
      const float* p = WhhL + ((size_t)(dir * 384 + row)) * 128 + kt * 32 + kw;
      union { f16x8 v; _Float16 s[8]; } Wh, Wl;
#pragma unroll
      for (int j = 0; j < 8; j++) {
        float v = p[j];
        _Float16 h = (_Float16)v;
        Wh.s[j] = h;
        Wl.s[j] = (_Float16)(v - (float)h);
      }
      whi[tt][kt] = Wh.v;
      wlo[tt][kt] = Wl.v;
    }
  }

  // ---- prologue: xg chunk = x_b @ WihD^T + bihD ----
  const u16*   wihD = wihL + (size_t)dir * 98304;        // [384,256]
  const float* bihD = bihL + dir * 384;
  float*       xgc  = xg + (size_t)(b * 2 + dir) * 24576; // [64,384]
  {
    const u16* xrow = xsrc + (size_t)(b * 64) * 256;
#pragma unroll
    for (int it = 0; it < 4; it++) {
      const int idx = it * 512 + tid;            // 2048 x 8 elems = 64x256
      const int r = idx >> 5, c8 = (idx & 31) * 8;
      *(uint4*)&xt[r * 264 + c8] = *(const uint4*)&xrow[r * 256 + c8];
    }
    __syncthreads();
#pragma unroll
    for (int tt = 0; tt < 3; tt++) {
      const int nt = tt * 8 + w;
      bf16x8 bfr[8];
#pragma unroll
      for (int kk = 0; kk < 8; kk++)
        bfr[kk] = *(const bf16x8*)&wihD[(size_t)(nt * 16 + lm) * 256 + kk * 32 + kw];
      const float bv = bihD[nt * 16 + lm];
      const int col = nt * 16 + lm;
#pragma unroll
      for (int mt = 0; mt < 4; mt++) {
        f32x4 a4 = (f32x4){0.f, 0.f, 0.f, 0.f};
#pragma unroll
        for (int kk = 0; kk < 8; kk++) {
          bf16x8 af = *(const bf16x8*)&xt[(mt * 16 + lm) * 264 + kk * 32 + kw];
          a4 = __builtin_amdgcn_mfma_f32_16x16x32_bf16(af, bfr[kk], a4, 0, 0, 0);
        }
        const int trow = mt * 16 + (l >> 4) * 4;
#pragma unroll
        for (int r = 0; r < 4; r++)
          xgc[(size_t)(trow + r) * 384 + col] = a4[r] + bv;
      }
    }
  }
  // biases for this lane's dim
  float bhr = 0.f, bhz = 0.f, bhn = 0.f;
  if (l < 16) {
    bhr = bhhL[dir * 384 + d];
    bhz = bhhL[dir * 384 + 128 + d];
    bhn = bhhL[dir * 384 + 256 + d];
  }
  // init h buffer 0
  if (tid < 128) { hbHi[0][tid] = (_Float16)0.f; hbLo[0][tid] = (_Float16)0.f; }
  __syncthreads();   // full drain: xg stores visible to all waves' reads

  const float* xbase = xgc + d;
  float xr = 0.f, xz = 0.f, xn = 0.f;
  if (l < 16) {
    const int t0 = dir ? 63 : 0;
    xr = xbase[t0 * 384];
    xz = xbase[t0 * 384 + 128];
    xn = xbase[t0 * 384 + 256];
  }
  float hold = 0.f, csum = 0.f;

  int cur = 0;
  for (int ti = 0; ti < 64; ti++) {
    const int t = dir ? (63 - ti) : ti;
    // prefetch next step's xg (stays in flight past the barrier)
    float nxr = 0.f, nxz = 0.f, nxn = 0.f;
    if (l < 16 && ti < 63) {
      const int tn = dir ? (62 - ti) : (ti + 1);
      nxr = xbase[tn * 384];
      nxz = xbase[tn * 384 + 128];
      nxn = xbase[tn * 384 + 256];
    }
    // A-frags: parity of this lane's A-row (lane&15) selects hi vs lo.
    const _Float16* hsrc = (l & 1) ? hbLo[cur] : hbHi[cur];
    f16x8 af[4];
#pragma unroll
    for (int kt = 0; kt < 4; kt++)
      af[kt] = *(const f16x8*)&hsrc[kt * 32 + kw];

    f32x4 aH[3], aL[3];
#pragma unroll
    for (int tt = 0; tt < 3; tt++) {
      aH[tt] = (f32x4){0.f, 0.f, 0.f, 0.f};
      aL[tt] = (f32x4){0.f, 0.f, 0.f, 0.f};
    }
#pragma unroll
    for (int kt = 0; kt < 4; kt++) {
#pragma unroll
      for (int tt = 0; tt < 3; tt++) {
        aH[tt] = __builtin_amdgcn_mfma_f32_16x16x32_f16(af[kt], whi[tt][kt], aH[tt], 0, 0, 0);
        aL[tt] = __builtin_amdgcn_mfma_f32_16x16x32_f16(af[kt], wlo[tt][kt], aL[tt], 0, 0, 0);
      }
    }
    const int nxt = cur ^ 1;
    if (l < 16) {
      // rows 0/1 of C = (hi-row)+(lo-row); W hi+lo passes summed.
      const float ghr = aH[0][0] + aH[0][1] + aL[0][0] + aL[0][1];
      const float ghz = aH[1][0] + aH[1][1] + aL[1][0] + aL[1][1];
      const float ghn = aH[2][0] + aH[2][1] + aL[2][0] + aL[2][1];
      const float rg = sigm(xr + bhr + ghr);
      const float zg = sigm(xz + bhz + ghz);
      const float ng = tanh_f(xn + rg * (ghn + bhn));
      const float hn = (1.f - zg) * ng + zg * hold;
      hold = hn;
      csum += hn;
      const _Float16 hh = (_Float16)hn;
      hbHi[nxt][d] = hh;
      hbLo[nxt][d] = (_Float16)(hn - (float)hh);
      const size_t oi = (size_t)(b * 64 + t) * 256 + dir * 128 + d;
      if (st_bf) st_bf[oi] = f2bf(hn);
      if (st_f)  st_f[oi]  = hn;
    }
    // LDS-only barrier: do NOT drain vmcnt (global stores / xg prefetch
    // keep flowing). lgkmcnt(0) makes the h-exchange visible before the
    // barrier; builtin s_barrier keeps compiler ordering semantics.
    asm volatile("s_waitcnt lgkmcnt(0)" ::: "memory");
    __builtin_amdgcn_s_barrier();
    cur = nxt;
    xr = nxr; xz = nxz; xn = nxn;
  }
  if (ctx != nullptr && l < 16)
    ctx[(size_t)b * 256 + dir * 128 + d] = csum;
}

// ---------------------------------------------------------------------------
// K4: final — out = softmax(context @ lin_w^T + lin_b) over O=2; alpha = 1.0.
// 128 blocks x 64 lanes; coalesced ctx reads + wave shuffle reduce.
// ---------------------------------------------------------------------------
__global__ __launch_bounds__(64) void k_final(
    const float* __restrict__ ctx, const float* __restrict__ lw,
    const float* __restrict__ lb, float* __restrict__ out,
    float* __restrict__ alpha) {
  const int b = blockIdx.x;    // 128
  const int l = threadIdx.x;   // 64
  float a0 = 0.f, a1 = 0.f;
#pragma unroll
  for (int q = 0; q < 4; q++) {
    const int k = q * 64 + l;
    const float c = ctx[b * 256 + k];
    a0 += c * lw[k];
    a1 += c * lw[256 + k];
  }
  for (int off = 32; off; off >>= 1) {
    a0 += __shfl_xor(a0, off, 64);
    a1 += __shfl_xor(a1, off, 64);
  }
  alpha[b * 64 + l] = 1.0f;
  if (l == 0) {
    a0 += lb[0];
    a1 += lb[1];
    const float m = fmaxf(a0, a1);
    const float e0 = __expf(a0 - m), e1 = __expf(a1 - m);
    const float s = e0 + e1;
    out[2 * b]     = e0 / s;
    out[2 * b + 1] = e1 / s;
  }
}

// ---------------------------------------------------------------------------
extern "C" void kernel_launch(void* const* d_in, const int* in_sizes, int n_in,
                              void* d_out, int out_size, void* d_ws, size_t ws_size,
                              hipStream_t stream) {
  const float* inp   = (const float*)d_in[0];   // [128,64,32,256]
  const float* convw = (const float*)d_in[1];   // [256]
  const float* convb = (const float*)d_in[2];   // [1]
  const float* embw  = (const float*)d_in[3];   // [256,256]
  const float* Wih   = (const float*)d_in[4];   // [2,2,384,256]
  const float* Whh   = (const float*)d_in[5];   // [2,2,384,128]
  const float* bih   = (const float*)d_in[6];   // [2,2,384]
  const float* bhh   = (const float*)d_in[7];   // [2,2,384]
  // d_in[8] att_w1: unused (softmax over size-1 axis == 1)
  const float* lw    = (const float*)d_in[9];   // [2,256]
  const float* lb    = (const float*)d_in[10];  // [2]

  char* ws = (char*)d_ws;
  u16*   convHi = (u16*)(ws);                         // 4 MiB; reused as states0
  u16*   convLo = (u16*)(ws + 4194304u);              // 4 MiB
  u16*   xbuf   = (u16*)(ws + 8388608u);              // 4 MiB
  u16*   embHi  = (u16*)(ws + 12582912u);             // 128 KiB
  u16*   embLo  = (u16*)(ws + 12713984u);             // 128 KiB
  u16*   wihB   = (u16*)(ws + 12845056u);             // 768 KiB
  float* xgbuf  = (float*)(ws + 13631488u);           // 24 MiB (per-block chunks)
  u16*   states0 = convHi;

  float* outp    = (float*)d_out;       // [128,2]
  float* statesO = outp + 256;          // [128,64,256]
  float* ctxO    = outp + 2097408;      // [128,256]
  float* alphaO  = outp + 2130176;      // [128,1,64]

  // 1) conv -> hi/lo split of conv_all; blocks 0..1535 also convert weights
  k_conv<<<8192, 256, 0, stream>>>(inp, convw, convb, convHi, convLo,
                                   embw, Wih, embHi, embLo, wihB);

  // 2) embed: x = clip((Ahi+Alo)@(Whi+Wlo)^T), bf16 out.  M=8192,N=256,K=256
  dim3 gE(128, 4);
  k_gemm<true, true, false, true, true><<<gE, 256, 0, stream>>>(
      convHi, convLo, embHi, embLo, nullptr, xbuf, 8192, 256, 256);

  // 3) GRU layer 0 (fused xg GEMM) -> states0 bf16 (ws)
  k_gru<<<256, 512, 0, stream>>>(xbuf, wihB, bih, Whh, bhh, xgbuf,
                                 states0, nullptr, nullptr);

  // 4) GRU layer 1 (fused xg GEMM) -> states fp32 (d_out) + context (d_out)
  k_gru<<<256, 512, 0, stream>>>(states0, wihB + 196608, bih + 768,
                                 Whh + 98304, bhh + 768, xgbuf,
                                 nullptr, statesO, ctxO);

  // 5) out softmax + alpha ones (fp32)
  k_final<<<128, 64, 0, stream>>>(ctxO, lw, lb, outp, alphaO);
}